// Round 1
// baseline (598.097 us; speedup 1.0000x reference)
//
#include <hip/hip_runtime.h>

typedef unsigned short u16;
typedef unsigned int u32;
typedef __attribute__((ext_vector_type(8))) short bf16x8;
typedef __attribute__((ext_vector_type(4))) float f32x4;

__device__ __forceinline__ u16 f2bf(float f) {
  u32 u = __builtin_bit_cast(u32, f);
  u = u + 0x7FFFu + ((u >> 16) & 1u);
  return (u16)(u >> 16);
}
__device__ __forceinline__ float bf2f(u16 s) {
  return __builtin_bit_cast(float, (u32)s << 16);
}

__device__ __forceinline__ void gload_lds16(const u16* g, u16* l) {
  __builtin_amdgcn_global_load_lds(
      (const __attribute__((address_space(1))) u32*)g,
      (__attribute__((address_space(3))) u32*)l, 16, 0, 0);
}

// ---------------------------------------------------------------------------
// fp32 -> bf16 weight conversion (n = 524288 for all four weight matrices)
// ---------------------------------------------------------------------------
__global__ __launch_bounds__(256) void k_cvt(const float* __restrict__ s,
                                             u16* __restrict__ d) {
  int i = (blockIdx.x * 256 + threadIdx.x) * 4;
  float4 v = *(const float4*)(s + i);
  u32 lo = (u32)f2bf(v.x) | ((u32)f2bf(v.y) << 16);
  u32 hi = (u32)f2bf(v.z) | ((u32)f2bf(v.w) << 16);
  uint2 o; o.x = lo; o.y = hi;
  *(uint2*)(d + i) = o;
}

// ---------------------------------------------------------------------------
// Fused: x [B,1024,64,64] fp32  ->  xT [B,4096,1024] bf16  (transpose+cast)
//                               ->  xpT [B,1024,1024] bf16 (2x2 maxpool + transpose)
// grid (C/32=32, H/8=8, B=8), 256 threads
// ---------------------------------------------------------------------------
__global__ __launch_bounds__(256) void k_transpose_pool(
    const float* __restrict__ x, u16* __restrict__ xT, u16* __restrict__ xpT) {
  __shared__ u16 lds[32][520];
  const int t = threadIdx.x;
  const int c0 = blockIdx.x * 32;
  const int h0 = blockIdx.y * 8;
  const int b = blockIdx.z;
  const float* xb = x + ((size_t)b * 1024 + c0) * 4096 + h0 * 64;
  // load 32 channels x 512 spatial, coalesced, cast to bf16 in LDS
  for (int ci = 0; ci < 32; ++ci) {
    float2 v = *(const float2*)(xb + (size_t)ci * 4096 + t * 2);
    lds[ci][t * 2] = f2bf(v.x);
    lds[ci][t * 2 + 1] = f2bf(v.y);
  }
  __syncthreads();
  // xT writes: [n][c], 32 contiguous bf16 per n-row
  {
    const int nsub = t >> 5, ci = t & 31;
    size_t base = ((size_t)b * 4096 + h0 * 64) * 1024 + c0 + ci;
    for (int ng = 0; ng < 64; ++ng) {
      int n = ng * 8 + nsub;
      xT[base + (size_t)n * 1024] = lds[ci][n];
    }
  }
  // pooled writes: m = (h0/2 + mhl)*32 + mw
  {
    const int msub = t >> 5, ci = t & 31;
    size_t base = ((size_t)b * 1024 + (h0 >> 1) * 32) * 1024 + c0 + ci;
    for (int mg = 0; mg < 16; ++mg) {
      int ml = mg * 8 + msub;  // 0..127
      int mhl = ml >> 5, mw = ml & 31;
      int n0 = mhl * 128 + mw * 2;
      float v = fmaxf(fmaxf(bf2f(lds[ci][n0]), bf2f(lds[ci][n0 + 1])),
                      fmaxf(bf2f(lds[ci][n0 + 64]), bf2f(lds[ci][n0 + 65])));
      xpT[base + (size_t)(mhl * 32 + mw) * 1024] = f2bf(v);
    }
  }
}

// ---------------------------------------------------------------------------
// NT GEMM: C[i,j] = scale * sum_k A[i,k]*B[j,k]  (+ bias_i | bias_j), bf16 out
// A [.,K] bf16 K-contig, B [.,K] bf16 K-contig, C row-major [.,N] bf16.
// 128x128 tile, BK=32, 256 threads (4 waves, 2x2), 16x16x32 MFMA.
// grid (N/128, M/128, batch)
// ---------------------------------------------------------------------------
template <int BIAS_MODE>  // 0 none, 1 row (bias[i]), 2 col (bias[j])
__global__ __launch_bounds__(256, 2) void gemm_nt(
    const u16* __restrict__ A, long aBS, const u16* __restrict__ Bm, long bBS,
    u16* __restrict__ Cm, long cBS, const float* __restrict__ bias, int N,
    int K, float scale) {
  __shared__ u16 Alds[128 * 32];
  __shared__ u16 Blds[128 * 32];
  const int t = threadIdx.x;
  const int b = blockIdx.z;
  const int bm = blockIdx.y, bn = blockIdx.x;
  const u16* Ab = A + (size_t)b * aBS + (size_t)bm * 128 * K;
  const u16* Bb = Bm + (size_t)b * bBS + (size_t)bn * 128 * K;

  const int lane = t & 63;
  const int w = t >> 6;
  const int wrow = w >> 1, wcol = w & 1;
  const int lr = lane & 15;
  const int kg = lane >> 4;

  f32x4 acc[4][4] = {};

  const int e0 = t * 8;        // staging elem idx, chunk 0
  const int r0 = e0 >> 5;      // row within tile
  const int k0i = e0 & 31;     // k within tile
  const int steps = K >> 5;
  for (int ks = 0; ks < steps; ++ks) {
    const int kb = ks * 32;
    gload_lds16(Ab + (size_t)r0 * K + kb + k0i, &Alds[e0]);
    gload_lds16(Ab + (size_t)(r0 + 64) * K + kb + k0i, &Alds[e0 + 2048]);
    gload_lds16(Bb + (size_t)r0 * K + kb + k0i, &Blds[e0]);
    gload_lds16(Bb + (size_t)(r0 + 64) * K + kb + k0i, &Blds[e0 + 2048]);
    __syncthreads();
    bf16x8 af[4], bfr[4];
#pragma unroll
    for (int i = 0; i < 4; ++i) {
      af[i] = *(const bf16x8*)&Alds[(wrow * 64 + i * 16 + lr) * 32 + kg * 8];
      bfr[i] = *(const bf16x8*)&Blds[(wcol * 64 + i * 16 + lr) * 32 + kg * 8];
    }
#pragma unroll
    for (int i = 0; i < 4; ++i)
#pragma unroll
      for (int j = 0; j < 4; ++j)
        acc[i][j] = __builtin_amdgcn_mfma_f32_16x16x32_bf16(af[i], bfr[j],
                                                            acc[i][j], 0, 0, 0);
    __syncthreads();
  }
  u16* Cb = Cm + (size_t)b * cBS;
#pragma unroll
  for (int i = 0; i < 4; ++i) {
#pragma unroll
    for (int j = 0; j < 4; ++j) {
      int row0 = bm * 128 + wrow * 64 + i * 16 + kg * 4;
      int col = bn * 128 + wcol * 64 + j * 16 + lr;
      float bj = (BIAS_MODE == 2) ? bias[col] : 0.f;
#pragma unroll
      for (int r = 0; r < 4; ++r) {
        float v = acc[i][j][r] * scale;
        if (BIAS_MODE == 1) v += bias[row0 + r];
        if (BIAS_MODE == 2) v += bj;
        Cb[(size_t)(row0 + r) * N + col] = f2bf(v);
      }
    }
  }
}

// ---------------------------------------------------------------------------
// Row softmax, in place. Rows of 1024 bf16, one wave per row, 4 rows/block.
// ---------------------------------------------------------------------------
__global__ __launch_bounds__(256) void k_softmax(u16* __restrict__ S) {
  const int t = threadIdx.x;
  const int lane = t & 63;
  const size_t row = (size_t)blockIdx.x * 4 + (t >> 6);
  u16* p = S + row * 1024 + lane * 16;
  uint4 d0 = *(const uint4*)p;
  uint4 d1 = *(const uint4*)(p + 8);
  u32 u[8] = {d0.x, d0.y, d0.z, d0.w, d1.x, d1.y, d1.z, d1.w};
  float v[16];
#pragma unroll
  for (int i = 0; i < 8; ++i) {
    v[2 * i] = bf2f((u16)(u[i] & 0xffff));
    v[2 * i + 1] = bf2f((u16)(u[i] >> 16));
  }
  float m = v[0];
#pragma unroll
  for (int i = 1; i < 16; ++i) m = fmaxf(m, v[i]);
  for (int o = 32; o > 0; o >>= 1) m = fmaxf(m, __shfl_xor(m, o));
  const float LOG2E = 1.44269504088896f;
  float s = 0.f;
#pragma unroll
  for (int i = 0; i < 16; ++i) {
    v[i] = exp2f((v[i] - m) * LOG2E);
    s += v[i];
  }
  for (int o = 32; o > 0; o >>= 1) s += __shfl_xor(s, o);
  float inv = 1.0f / s;
#pragma unroll
  for (int i = 0; i < 8; ++i)
    u[i] = (u32)f2bf(v[2 * i] * inv) | ((u32)f2bf(v[2 * i + 1] * inv) << 16);
  uint4 o0; o0.x = u[0]; o0.y = u[1]; o0.z = u[2]; o0.w = u[3];
  uint4 o1; o1.x = u[4]; o1.y = u[5]; o1.z = u[6]; o1.w = u[7];
  *(uint4*)p = o0;
  *(uint4*)(p + 8) = o1;
}

// ---------------------------------------------------------------------------
// BN stats: per channel o, sum & sumsq of z[b][o][n] over b,n. block per o.
// ---------------------------------------------------------------------------
__global__ __launch_bounds__(256) void k_stats(const u16* __restrict__ z,
                                               float2* __restrict__ stats) {
  const int o = blockIdx.x;
  const int t = threadIdx.x;
  float s = 0.f, q = 0.f;
  for (int b = 0; b < 8; ++b) {
    const u16* p = z + ((size_t)b * 1024 + o) * 4096;
    for (int i = t * 4; i < 4096; i += 1024) {
      uint2 d = *(const uint2*)(p + i);
      float a0 = bf2f((u16)(d.x & 0xffff)), a1 = bf2f((u16)(d.x >> 16));
      float a2 = bf2f((u16)(d.y & 0xffff)), a3 = bf2f((u16)(d.y >> 16));
      s += a0 + a1 + a2 + a3;
      q += a0 * a0 + a1 * a1 + a2 * a2 + a3 * a3;
    }
  }
  for (int o2 = 32; o2 > 0; o2 >>= 1) {
    s += __shfl_xor(s, o2);
    q += __shfl_xor(q, o2);
  }
  __shared__ float2 red[4];
  if ((t & 63) == 0) red[t >> 6] = make_float2(s, q);
  __syncthreads();
  if (t == 0) {
    float S_ = 0.f, Q_ = 0.f;
    for (int i = 0; i < 4; ++i) { S_ += red[i].x; Q_ += red[i].y; }
    stats[o] = make_float2(S_, Q_);
  }
}

// ---------------------------------------------------------------------------
// BN apply + residual: out = x + (z-mean)*rsqrt(var+eps)*gamma + beta
// ---------------------------------------------------------------------------
__global__ __launch_bounds__(256) void k_apply(
    const float* __restrict__ x, const u16* __restrict__ z,
    const float2* __restrict__ stats, const float* __restrict__ gamma,
    const float* __restrict__ beta, float* __restrict__ out) {
  size_t i4 = (size_t)blockIdx.x * 256 + threadIdx.x;
  size_t e = i4 * 4;
  int c = (int)((e >> 12) & 1023);
  float2 st = stats[c];
  const float cnt = 1.0f / 32768.0f;
  float mean = st.x * cnt;
  float var = st.y * cnt - mean * mean;
  float g = rsqrtf(var + 1e-5f) * gamma[c];
  float sh = beta[c] - mean * g;
  float4 xv = *(const float4*)(x + e);
  uint2 zd = *(const uint2*)(z + e);
  float z0 = bf2f((u16)(zd.x & 0xffff)), z1 = bf2f((u16)(zd.x >> 16));
  float z2 = bf2f((u16)(zd.y & 0xffff)), z3 = bf2f((u16)(zd.y >> 16));
  float4 ov;
  ov.x = xv.x + z0 * g + sh;
  ov.y = xv.y + z1 * g + sh;
  ov.z = xv.z + z2 * g + sh;
  ov.w = xv.w + z3 * g + sh;
  *(float4*)(out + e) = ov;
}

// ---------------------------------------------------------------------------
extern "C" void kernel_launch(void* const* d_in, const int* in_sizes, int n_in,
                              void* d_out, int out_size, void* d_ws,
                              size_t ws_size, hipStream_t stream) {
  const float* x = (const float*)d_in[0];
  const float* theta_w = (const float*)d_in[1];
  const float* theta_b = (const float*)d_in[2];
  const float* phi_w = (const float*)d_in[3];
  const float* phi_b = (const float*)d_in[4];
  const float* g_w = (const float*)d_in[5];
  const float* g_b = (const float*)d_in[6];
  const float* wz_w = (const float*)d_in[7];
  const float* wz_b = (const float*)d_in[8];
  const float* gamma = (const float*)d_in[9];
  const float* beta = (const float*)d_in[10];
  float* out = (float*)d_out;

  char* w = (char*)d_ws;
  const size_t MiB = (size_t)1 << 20;
  u16* WT = (u16*)(w + 0 * MiB);
  u16* WP = (u16*)(w + 1 * MiB);
  u16* WG = (u16*)(w + 2 * MiB);
  u16* WZ = (u16*)(w + 3 * MiB);
  u16* XT = (u16*)(w + 4 * MiB);      // [8][4096][1024] 64 MiB
  u16* XPT = (u16*)(w + 68 * MiB);    // [8][1024][1024] 16 MiB
  u16* THETA = (u16*)(w + 84 * MiB);  // [8][4096][512]  32 MiB
  u16* PHI = (u16*)(w + 116 * MiB);   // [8][1024][512]   8 MiB
  u16* G = (u16*)(w + 124 * MiB);     // [8][512][1024]   8 MiB
  u16* S = XT;                        // reuse xT region (dead after theta GEMM)
  u16* YT = (u16*)(w + 132 * MiB);    // [8][4096][512]  32 MiB
  u16* Z = S;                         // reuse again (P dead after yT GEMM)
  float2* stats = (float2*)(w + 164 * MiB);

  // weights -> bf16
  k_cvt<<<512, 256, 0, stream>>>(theta_w, WT);
  k_cvt<<<512, 256, 0, stream>>>(phi_w, WP);
  k_cvt<<<512, 256, 0, stream>>>(g_w, WG);
  k_cvt<<<512, 256, 0, stream>>>(wz_w, WZ);
  // x -> xT, xpT
  k_transpose_pool<<<dim3(32, 8, 8), 256, 0, stream>>>(x, XT, XPT);
  // thetaT[n,ci] = xT @ theta_w^T + theta_b   (bias over col=ci)
  gemm_nt<2><<<dim3(4, 32, 8), 256, 0, stream>>>(
      XT, (long)4096 * 1024, WT, 0, THETA, (long)4096 * 512, theta_b, 512,
      1024, 1.0f);
  // phiT[m,ci]
  gemm_nt<2><<<dim3(4, 8, 8), 256, 0, stream>>>(
      XPT, (long)1024 * 1024, WP, 0, PHI, (long)1024 * 512, phi_b, 512, 1024,
      1.0f);
  // g[ci,m]  (bias over row=ci)
  gemm_nt<1><<<dim3(8, 4, 8), 256, 0, stream>>>(
      WG, 0, XPT, (long)1024 * 1024, G, (long)512 * 1024, g_b, 1024, 1024,
      1.0f);
  // S[n,m] = thetaT . phiT^T * scale
  gemm_nt<0><<<dim3(8, 32, 8), 256, 0, stream>>>(
      THETA, (long)4096 * 512, PHI, (long)1024 * 512, S, (long)4096 * 1024,
      nullptr, 1024, 512, 0.04419417382415922f);
  // softmax rows (in place -> P)
  k_softmax<<<8192, 256, 0, stream>>>(S);
  // yT[n,ci] = P . g^T
  gemm_nt<0><<<dim3(4, 32, 8), 256, 0, stream>>>(
      S, (long)4096 * 1024, G, (long)512 * 1024, YT, (long)4096 * 512, nullptr,
      512, 1024, 1.0f);
  // z[o,n] = wz . yT^T + wz_b   (bias over row=o)
  gemm_nt<1><<<dim3(32, 8, 8), 256, 0, stream>>>(
      WZ, 0, YT, (long)4096 * 512, Z, (long)1024 * 4096, wz_b, 4096, 512,
      1.0f);
  // BN stats + apply + residual
  k_stats<<<1024, 256, 0, stream>>>(Z, stats);
  k_apply<<<32768, 256, 0, stream>>>(x, Z, stats, gamma, beta, out);

  (void)in_sizes; (void)n_in; (void)out_size; (void)ws_size;
}

// Round 2
// 579.468 us; speedup vs baseline: 1.0321x; 1.0321x over previous
//
#include <hip/hip_runtime.h>

typedef unsigned short u16;
typedef unsigned int u32;
typedef __attribute__((ext_vector_type(8))) short bf16x8;
typedef __attribute__((ext_vector_type(4))) float f32x4;

__device__ __forceinline__ u16 f2bf(float f) {
  u32 u = __builtin_bit_cast(u32, f);
  u = u + 0x7FFFu + ((u >> 16) & 1u);
  return (u16)(u >> 16);
}
__device__ __forceinline__ float bf2f(u16 s) {
  return __builtin_bit_cast(float, (u32)s << 16);
}

__device__ __forceinline__ void gload_lds16(const u16* g, u16* l) {
  __builtin_amdgcn_global_load_lds(
      (const __attribute__((address_space(1))) u32*)g,
      (__attribute__((address_space(3))) u32*)l, 16, 0, 0);
}

// ---------------------------------------------------------------------------
// fp32 -> bf16 weight conversion
// ---------------------------------------------------------------------------
__global__ __launch_bounds__(256) void k_cvt(const float* __restrict__ s,
                                             u16* __restrict__ d) {
  int i = (blockIdx.x * 256 + threadIdx.x) * 4;
  float4 v = *(const float4*)(s + i);
  u32 lo = (u32)f2bf(v.x) | ((u32)f2bf(v.y) << 16);
  u32 hi = (u32)f2bf(v.z) | ((u32)f2bf(v.w) << 16);
  uint2 o; o.x = lo; o.y = hi;
  *(uint2*)(d + i) = o;
}

// ---------------------------------------------------------------------------
// Fused: x [B,1024,64,64] fp32 -> xT [B,4096,1024] bf16 (transpose+cast)
//                              -> xpT [B,1024,1024] bf16 (2x2 maxpool + T)
// Tile: 64 channels x 128 spatial (2 h-rows). grid (C/64=16, H/2=32, B=8).
// LDS layout: ldsT[n][c ^ 8*((n>>2)&7)], 128 x 64 u16 = 16 KB.
// All global stores are 16B bf16x8.
// ---------------------------------------------------------------------------
__global__ __launch_bounds__(256) void k_transpose_pool(
    const float* __restrict__ x, u16* __restrict__ xT, u16* __restrict__ xpT) {
  __shared__ u16 lds[128 * 64];
  const int t = threadIdx.x;
  const int c0 = blockIdx.x * 64;
  const int by = blockIdx.y;        // h0 = by*2
  const int b = blockIdx.z;

  // phase 1: load 64c x 128n fp32 coalesced, cast, store swizzled-transposed
  {
    const int nf = (t & 31) * 4;          // local n base (0..124)
    const int swz = 8 * (t & 7);          // = 8*(((nf)>>2)&7)
    const float* xb =
        x + ((size_t)(b * 1024 + c0 + (t >> 5)) * 4096) + by * 128 + nf;
#pragma unroll
    for (int u = 0; u < 8; ++u) {
      const int c_l = (t >> 5) + 8 * u;
      float4 v = *(const float4*)(xb + (size_t)(8 * u) * 4096);
      const int col = c_l ^ swz;
      lds[(nf + 0) * 64 + col] = f2bf(v.x);
      lds[(nf + 1) * 64 + col] = f2bf(v.y);
      lds[(nf + 2) * 64 + col] = f2bf(v.z);
      lds[(nf + 3) * 64 + col] = f2bf(v.w);
    }
  }
  __syncthreads();
  // phase 2a: xT writes, 16B per lane, 4 iters
  {
#pragma unroll
    for (int v = 0; v < 4; ++v) {
      const int idx = t + 256 * v;        // 0..1023
      const int n_l = idx >> 3;           // 0..127
      const int cb = (idx & 7) * 8;       // 0..56
      const int col = cb ^ (8 * ((n_l >> 2) & 7));
      bf16x8 d = *(const bf16x8*)&lds[n_l * 64 + col];
      *(bf16x8*)&xT[((size_t)b * 4096 + by * 128 + n_l) * 1024 + c0 + cb] = d;
    }
  }
  // phase 2b: pooled writes, 16B per lane, 1 iter (32 m x 8 cblk = 256)
  {
    const int m_w = t >> 3;               // 0..31
    const int cb = (t & 7) * 8;
    const int na = 2 * m_w, nb = na + 1, nc = na + 64, nd = na + 65;
    bf16x8 va = *(const bf16x8*)&lds[na * 64 + (cb ^ (8 * ((na >> 2) & 7)))];
    bf16x8 vb = *(const bf16x8*)&lds[nb * 64 + (cb ^ (8 * ((nb >> 2) & 7)))];
    bf16x8 vc = *(const bf16x8*)&lds[nc * 64 + (cb ^ (8 * ((nc >> 2) & 7)))];
    bf16x8 vd = *(const bf16x8*)&lds[nd * 64 + (cb ^ (8 * ((nd >> 2) & 7)))];
    bf16x8 o;
#pragma unroll
    for (int j = 0; j < 8; ++j) {
      float m = fmaxf(fmaxf(bf2f((u16)va[j]), bf2f((u16)vb[j])),
                      fmaxf(bf2f((u16)vc[j]), bf2f((u16)vd[j])));
      o[j] = (short)f2bf(m);
    }
    *(bf16x8*)&xpT[((size_t)b * 1024 + by * 32 + m_w) * 1024 + c0 + cb] = o;
  }
}

// ---------------------------------------------------------------------------
// NT GEMM: C[i,j] = scale * sum_k A[i,k]*B[j,k]  (+ bias_i | bias_j), bf16 out
// A [.,K] bf16 K-contig, B [.,K] bf16 K-contig, C row-major [.,N] bf16.
// 128x128 tile, BK=32, 256 threads (4 waves, 2x2), 16x16x32 MFMA.
// Double-buffered LDS, prefetch-before-compute, ONE barrier per K-step (T3-min).
// grid (N/128, M/128, batch)
// ---------------------------------------------------------------------------
template <int BIAS_MODE>  // 0 none, 1 row (bias[i]), 2 col (bias[j])
__global__ __launch_bounds__(256, 2) void gemm_nt(
    const u16* __restrict__ A, long aBS, const u16* __restrict__ Bm, long bBS,
    u16* __restrict__ Cm, long cBS, const float* __restrict__ bias, int N,
    int K, float scale) {
  __shared__ u16 Alds[2][128 * 32];
  __shared__ u16 Blds[2][128 * 32];
  const int t = threadIdx.x;
  const int b = blockIdx.z;
  const int bm = blockIdx.y, bn = blockIdx.x;
  const u16* Ab = A + (size_t)b * aBS + (size_t)bm * 128 * K;
  const u16* Bb = Bm + (size_t)b * bBS + (size_t)bn * 128 * K;

  const int lane = t & 63;
  const int w = t >> 6;
  const int wrow = w >> 1, wcol = w & 1;
  const int lr = lane & 15;
  const int kg = lane >> 4;

  f32x4 acc[4][4] = {};

  const int e0 = t * 8;        // staging elem idx, chunk 0
  const int r0 = e0 >> 5;      // row within tile
  const int k0i = e0 & 31;     // k within tile
  const int steps = K >> 5;

#define STAGE(buf, ks)                                                   \
  do {                                                                   \
    const int kb = (ks) * 32;                                            \
    gload_lds16(Ab + (size_t)r0 * K + kb + k0i, &Alds[buf][e0]);         \
    gload_lds16(Ab + (size_t)(r0 + 64) * K + kb + k0i,                   \
                &Alds[buf][e0 + 2048]);                                  \
    gload_lds16(Bb + (size_t)r0 * K + kb + k0i, &Blds[buf][e0]);         \
    gload_lds16(Bb + (size_t)(r0 + 64) * K + kb + k0i,                   \
                &Blds[buf][e0 + 2048]);                                  \
  } while (0)

  STAGE(0, 0);
  for (int ks = 0; ks < steps; ++ks) {
    const int cur = ks & 1;
    // __syncthreads drains vmcnt(0): buf[cur] staged & everyone's reads of
    // buf[cur^1] retired (they completed before each wave's MFMA waits).
    __syncthreads();
    if (ks + 1 < steps) STAGE(cur ^ 1, ks + 1);
    bf16x8 af[4], bfr[4];
#pragma unroll
    for (int i = 0; i < 4; ++i) {
      af[i] =
          *(const bf16x8*)&Alds[cur][(wrow * 64 + i * 16 + lr) * 32 + kg * 8];
      bfr[i] =
          *(const bf16x8*)&Blds[cur][(wcol * 64 + i * 16 + lr) * 32 + kg * 8];
    }
#pragma unroll
    for (int i = 0; i < 4; ++i)
#pragma unroll
      for (int j = 0; j < 4; ++j)
        acc[i][j] = __builtin_amdgcn_mfma_f32_16x16x32_bf16(af[i], bfr[j],
                                                            acc[i][j], 0, 0, 0);
  }
#undef STAGE

  u16* Cb = Cm + (size_t)b * cBS;
#pragma unroll
  for (int i = 0; i < 4; ++i) {
#pragma unroll
    for (int j = 0; j < 4; ++j) {
      int row0 = bm * 128 + wrow * 64 + i * 16 + kg * 4;
      int col = bn * 128 + wcol * 64 + j * 16 + lr;
      float bj = (BIAS_MODE == 2) ? bias[col] : 0.f;
#pragma unroll
      for (int r = 0; r < 4; ++r) {
        float v = acc[i][j][r] * scale;
        if (BIAS_MODE == 1) v += bias[row0 + r];
        if (BIAS_MODE == 2) v += bj;
        Cb[(size_t)(row0 + r) * N + col] = f2bf(v);
      }
    }
  }
}

// ---------------------------------------------------------------------------
// Row softmax, in place. Rows of 1024 bf16, one wave per row, 4 rows/block.
// ---------------------------------------------------------------------------
__global__ __launch_bounds__(256) void k_softmax(u16* __restrict__ S) {
  const int t = threadIdx.x;
  const int lane = t & 63;
  const size_t row = (size_t)blockIdx.x * 4 + (t >> 6);
  u16* p = S + row * 1024 + lane * 16;
  uint4 d0 = *(const uint4*)p;
  uint4 d1 = *(const uint4*)(p + 8);
  u32 u[8] = {d0.x, d0.y, d0.z, d0.w, d1.x, d1.y, d1.z, d1.w};
  float v[16];
#pragma unroll
  for (int i = 0; i < 8; ++i) {
    v[2 * i] = bf2f((u16)(u[i] & 0xffff));
    v[2 * i + 1] = bf2f((u16)(u[i] >> 16));
  }
  float m = v[0];
#pragma unroll
  for (int i = 1; i < 16; ++i) m = fmaxf(m, v[i]);
  for (int o = 32; o > 0; o >>= 1) m = fmaxf(m, __shfl_xor(m, o));
  const float LOG2E = 1.44269504088896f;
  float s = 0.f;
#pragma unroll
  for (int i = 0; i < 16; ++i) {
    v[i] = exp2f((v[i] - m) * LOG2E);
    s += v[i];
  }
  for (int o = 32; o > 0; o >>= 1) s += __shfl_xor(s, o);
  float inv = 1.0f / s;
#pragma unroll
  for (int i = 0; i < 8; ++i)
    u[i] = (u32)f2bf(v[2 * i] * inv) | ((u32)f2bf(v[2 * i + 1] * inv) << 16);
  uint4 o0; o0.x = u[0]; o0.y = u[1]; o0.z = u[2]; o0.w = u[3];
  uint4 o1; o1.x = u[4]; o1.y = u[5]; o1.z = u[6]; o1.w = u[7];
  *(uint4*)p = o0;
  *(uint4*)(p + 8) = o1;
}

// ---------------------------------------------------------------------------
// BN stats: per channel o, sum & sumsq of z[b][o][n] over b,n. block per o.
// ---------------------------------------------------------------------------
__global__ __launch_bounds__(256) void k_stats(const u16* __restrict__ z,
                                               float2* __restrict__ stats) {
  const int o = blockIdx.x;
  const int t = threadIdx.x;
  float s = 0.f, q = 0.f;
  for (int b = 0; b < 8; ++b) {
    const u16* p = z + ((size_t)b * 1024 + o) * 4096;
    for (int i = t * 4; i < 4096; i += 1024) {
      uint2 d = *(const uint2*)(p + i);
      float a0 = bf2f((u16)(d.x & 0xffff)), a1 = bf2f((u16)(d.x >> 16));
      float a2 = bf2f((u16)(d.y & 0xffff)), a3 = bf2f((u16)(d.y >> 16));
      s += a0 + a1 + a2 + a3;
      q += a0 * a0 + a1 * a1 + a2 * a2 + a3 * a3;
    }
  }
  for (int o2 = 32; o2 > 0; o2 >>= 1) {
    s += __shfl_xor(s, o2);
    q += __shfl_xor(q, o2);
  }
  __shared__ float2 red[4];
  if ((t & 63) == 0) red[t >> 6] = make_float2(s, q);
  __syncthreads();
  if (t == 0) {
    float S_ = 0.f, Q_ = 0.f;
    for (int i = 0; i < 4; ++i) { S_ += red[i].x; Q_ += red[i].y; }
    stats[o] = make_float2(S_, Q_);
  }
}

// ---------------------------------------------------------------------------
// BN apply + residual: out = x + (z-mean)*rsqrt(var+eps)*gamma + beta
// ---------------------------------------------------------------------------
__global__ __launch_bounds__(256) void k_apply(
    const float* __restrict__ x, const u16* __restrict__ z,
    const float2* __restrict__ stats, const float* __restrict__ gamma,
    const float* __restrict__ beta, float* __restrict__ out) {
  size_t i4 = (size_t)blockIdx.x * 256 + threadIdx.x;
  size_t e = i4 * 4;
  int c = (int)((e >> 12) & 1023);
  float2 st = stats[c];
  const float cnt = 1.0f / 32768.0f;
  float mean = st.x * cnt;
  float var = st.y * cnt - mean * mean;
  float g = rsqrtf(var + 1e-5f) * gamma[c];
  float sh = beta[c] - mean * g;
  float4 xv = *(const float4*)(x + e);
  uint2 zd = *(const uint2*)(z + e);
  float z0 = bf2f((u16)(zd.x & 0xffff)), z1 = bf2f((u16)(zd.x >> 16));
  float z2 = bf2f((u16)(zd.y & 0xffff)), z3 = bf2f((u16)(zd.y >> 16));
  float4 ov;
  ov.x = xv.x + z0 * g + sh;
  ov.y = xv.y + z1 * g + sh;
  ov.z = xv.z + z2 * g + sh;
  ov.w = xv.w + z3 * g + sh;
  *(float4*)(out + e) = ov;
}

// ---------------------------------------------------------------------------
extern "C" void kernel_launch(void* const* d_in, const int* in_sizes, int n_in,
                              void* d_out, int out_size, void* d_ws,
                              size_t ws_size, hipStream_t stream) {
  const float* x = (const float*)d_in[0];
  const float* theta_w = (const float*)d_in[1];
  const float* theta_b = (const float*)d_in[2];
  const float* phi_w = (const float*)d_in[3];
  const float* phi_b = (const float*)d_in[4];
  const float* g_w = (const float*)d_in[5];
  const float* g_b = (const float*)d_in[6];
  const float* wz_w = (const float*)d_in[7];
  const float* wz_b = (const float*)d_in[8];
  const float* gamma = (const float*)d_in[9];
  const float* beta = (const float*)d_in[10];
  float* out = (float*)d_out;

  char* w = (char*)d_ws;
  const size_t MiB = (size_t)1 << 20;
  u16* WT = (u16*)(w + 0 * MiB);
  u16* WP = (u16*)(w + 1 * MiB);
  u16* WG = (u16*)(w + 2 * MiB);
  u16* WZ = (u16*)(w + 3 * MiB);
  u16* XT = (u16*)(w + 4 * MiB);      // [8][4096][1024] 64 MiB
  u16* XPT = (u16*)(w + 68 * MiB);    // [8][1024][1024] 16 MiB
  u16* THETA = (u16*)(w + 84 * MiB);  // [8][4096][512]  32 MiB
  u16* PHI = (u16*)(w + 116 * MiB);   // [8][1024][512]   8 MiB
  u16* G = (u16*)(w + 124 * MiB);     // [8][512][1024]   8 MiB
  u16* S = XT;                        // reuse xT region (dead after theta GEMM)
  u16* YT = (u16*)(w + 132 * MiB);    // [8][4096][512]  32 MiB
  u16* Z = S;                         // reuse again (P dead after yT GEMM)
  float2* stats = (float2*)(w + 164 * MiB);

  // weights -> bf16
  k_cvt<<<512, 256, 0, stream>>>(theta_w, WT);
  k_cvt<<<512, 256, 0, stream>>>(phi_w, WP);
  k_cvt<<<512, 256, 0, stream>>>(g_w, WG);
  k_cvt<<<512, 256, 0, stream>>>(wz_w, WZ);
  // x -> xT, xpT
  k_transpose_pool<<<dim3(16, 32, 8), 256, 0, stream>>>(x, XT, XPT);
  // thetaT[n,ci] = xT @ theta_w^T + theta_b   (bias over col=ci)
  gemm_nt<2><<<dim3(4, 32, 8), 256, 0, stream>>>(
      XT, (long)4096 * 1024, WT, 0, THETA, (long)4096 * 512, theta_b, 512,
      1024, 1.0f);
  // phiT[m,ci]
  gemm_nt<2><<<dim3(4, 8, 8), 256, 0, stream>>>(
      XPT, (long)1024 * 1024, WP, 0, PHI, (long)1024 * 512, phi_b, 512, 1024,
      1.0f);
  // g[ci,m]  (bias over row=ci)
  gemm_nt<1><<<dim3(8, 4, 8), 256, 0, stream>>>(
      WG, 0, XPT, (long)1024 * 1024, G, (long)512 * 1024, g_b, 1024, 1024,
      1.0f);
  // S[n,m] = thetaT . phiT^T * scale
  gemm_nt<0><<<dim3(8, 32, 8), 256, 0, stream>>>(
      THETA, (long)4096 * 512, PHI, (long)1024 * 512, S, (long)4096 * 1024,
      nullptr, 1024, 512, 0.04419417382415922f);
  // softmax rows (in place -> P)
  k_softmax<<<8192, 256, 0, stream>>>(S);
  // yT[n,ci] = P . g^T
  gemm_nt<0><<<dim3(4, 32, 8), 256, 0, stream>>>(
      S, (long)4096 * 1024, G, (long)512 * 1024, YT, (long)4096 * 512, nullptr,
      512, 1024, 1.0f);
  // z[o,n] = wz . yT^T + wz_b   (bias over row=o)
  gemm_nt<1><<<dim3(32, 8, 8), 256, 0, stream>>>(
      WZ, 0, YT, (long)4096 * 512, Z, (long)1024 * 4096, wz_b, 4096, 512,
      1.0f);
  // BN stats + apply + residual
  k_stats<<<1024, 256, 0, stream>>>(Z, stats);
  k_apply<<<32768, 256, 0, stream>>>(x, Z, stats, gamma, beta, out);

  (void)in_sizes; (void)n_in; (void)out_size; (void)ws_size;
}